// Round 3
// baseline (220.699 us; speedup 1.0000x reference)
//
#include <hip/hip_runtime.h>
#include <hip/hip_bf16.h>

// Problem constants
#define NA 1024   // n_atom
#define NT 256    // n_token
#define CS 384    // c_s
#define CZ 128    // c_z
#define CA 128    // c_atom
#define CP 16     // c_atom_pair

typedef __attribute__((ext_vector_type(8))) short short8;
typedef __attribute__((ext_vector_type(4))) float f32x4;

__device__ __forceinline__ float bfu(unsigned short v){ return __uint_as_float(((unsigned)v) << 16); }
__device__ __forceinline__ unsigned short f2bf(float f){
  unsigned u = __float_as_uint(f);
  return (unsigned short)((u + 0x7fffu + ((u >> 16) & 1u)) >> 16); // RNE
}
__device__ __forceinline__ unsigned pack2(float lo, float hi){
  return (unsigned)f2bf(lo) | ((unsigned)f2bf(hi) << 16);
}

__device__ __forceinline__ int lbound(const unsigned short* tokL, int key){
  int lo = 0, hi = NA;
  while (lo < hi) { int mid = (lo + hi) >> 1; if ((int)tokL[mid] < key) lo = mid + 1; else hi = mid; }
  return lo;
}

// ---------------------------------------------------------------------------
// prep: blocks [0,256)   role A: tok16[a] = argmax_t a2t[a,t]  (wave per atom)
//       blocks [256,512) role B: ytok[t,:] = LN_s(s_trunk[t])@W_s  (bf16 in ws)
// ws use: tok16 2 KB + ytok 64 KB = 66 KB
// ---------------------------------------------------------------------------
__global__ __launch_bounds__(256) void prep_kernel(
    const float* __restrict__ a2t,
    const float* __restrict__ s_trunk,
    const float* __restrict__ lnsw,
    const float* __restrict__ lnsb,
    const float* __restrict__ Ws,
    unsigned short* __restrict__ tok16,
    unsigned short* __restrict__ ytok)
{
  __shared__ float redS[4], redQ[4];
  __shared__ float lnbuf[CS];
  __shared__ float part[CA];

  const int blk  = blockIdx.x;
  const int tid  = threadIdx.x;
  const int lane = tid & 63;
  const int wv   = tid >> 6;

  if (blk < 256) {
    // ---- role A: one wave per atom; lane covers 4 one-hot f32 entries ----
    int a = blk * 4 + wv;
    float4 u = ((const float4*)(a2t + (size_t)a * NT))[lane];
    bool hit = (u.x != 0.f) | (u.y != 0.f) | (u.z != 0.f) | (u.w != 0.f);
    unsigned long long m = __ballot(hit);
    int fl = __ffsll(m) - 1;
    if (lane == fl) {
      int t = lane * 4;
      if (u.x != 0.f)      { /* +0 */ }
      else if (u.y != 0.f) t += 1;
      else if (u.z != 0.f) t += 2;
      else                 t += 3;
      tok16[a] = (unsigned short)t;
    }
  } else {
    // ---- role B: one block per token ----
    int tk = blk - 256;
    float f0 = 0.f, f1 = 0.f;
    if (tid < 192) {
      float2 v = ((const float2*)(s_trunk + (size_t)tk * CS))[tid];
      f0 = v.x; f1 = v.y;
    }
    float s = f0 + f1;
    float q = f0 * f0 + f1 * f1;
    #pragma unroll
    for (int m = 1; m < 64; m <<= 1) { s += __shfl_xor(s, m); q += __shfl_xor(q, m); }
    if (lane == 0) { redS[wv] = s; redQ[wv] = q; }
    __syncthreads();
    if (tid == 0) {
      float S = redS[0] + redS[1] + redS[2] + redS[3];
      float Q = redQ[0] + redQ[1] + redQ[2] + redQ[3];
      float mean = S * (1.f / 384.f);
      float var  = Q * (1.f / 384.f) - mean * mean;
      redS[0] = mean;
      redQ[0] = rsqrtf(var + 1e-5f);
    }
    __syncthreads();
    float mean = redS[0], rstd = redQ[0];
    if (tid < 192) {
      float2 w2 = ((const float2*)lnsw)[tid];
      float2 b2 = ((const float2*)lnsb)[tid];
      lnbuf[2 * tid]     = fmaf((f0 - mean) * rstd, w2.x, b2.x);
      lnbuf[2 * tid + 1] = fmaf((f1 - mean) * rstd, w2.y, b2.y);
    }
    __syncthreads();
    int j = tid & 127, half = tid >> 7;
    float acc = 0.f;
    int c0 = half * 192;
    #pragma unroll 8
    for (int c = c0; c < c0 + 192; ++c)
      acc = fmaf(lnbuf[c], Ws[(size_t)c * CA + j], acc);
    if (half) part[j] = acc;
    __syncthreads();
    if (!half) ytok[(size_t)tk * CA + j] = f2bf(acc + part[j]);
  }
}

// ---------------------------------------------------------------------------
// main: blocks [0,1024)     block = (token t, 64-token m-tile):
//                           w[t,m,:] via bf16 MFMA into LDS, then broadcast-add
//                           into plm rows a in run(t), cols b in run(m-tile).
//       blocks [1024,1536)  cl_out = cl + ytok[tok[a]]
//       blocks [1536,2048)  ql_out = ql + rl @ W_r
// ---------------------------------------------------------------------------
__global__ __launch_bounds__(256) void main_kernel(
    const float* __restrict__ cl,
    const float* __restrict__ plm,
    const float* __restrict__ ql,
    const float* __restrict__ rl,
    const float* __restrict__ Wr,
    const float* __restrict__ zij,
    const float* __restrict__ lnzw,
    const float* __restrict__ lnzb,
    const float* __restrict__ Wz,
    const unsigned short* __restrict__ tok16,
    const unsigned short* __restrict__ ytok,
    float* __restrict__ out)
{
  const int blk = blockIdx.x;
  const int tid = threadIdx.x;

  if (blk < 1024) {
    __shared__ unsigned short tokL[NA];                // 2 KB
    __shared__ unsigned short stage[4 * 16 * 136];     // 17.4 KB, stride 136 vs bank aliasing
    __shared__ float wlds[64 * 16];                    // 4 KB

    const int lane = tid & 63;
    const int wv   = tid >> 6;
    const int t    = blk >> 2;
    const int m0   = (blk & 3) << 6;

    // stage tok[] into LDS (256 threads x 4 u16)
    ((uint2*)tokL)[tid] = ((const uint2*)tok16)[tid];
    __syncthreads();

    int s = lbound(tokL, t);
    int e = lbound(tokL, t + 1);
    if (s == e) return;                    // no atoms for this token (uniform exit)
    int S = lbound(tokL, m0);
    int E = lbound(tokL, m0 + 64);
    if (S == E) return;                    // no atoms in this m-tile (uniform exit)

    // ---- w[t, m0+wv*16+r, :] = LN_z(zij[t,m])@W_z via MFMA, results -> wlds ----
    {
      int r = lane >> 2, q = lane & 3;     // 4 lanes per row, 32 channels each
      int mrow = m0 + wv * 16 + r;
      const float4* zp = (const float4*)(zij + ((size_t)t * NT + mrow) * CZ + q * 32);
      float x[32];
      float sm = 0.f, ss = 0.f;
      #pragma unroll
      for (int i = 0; i < 8; ++i) {
        float4 v = zp[i];
        x[4 * i]     = v.x; x[4 * i + 1] = v.y;
        x[4 * i + 2] = v.z; x[4 * i + 3] = v.w;
        sm += (v.x + v.y) + (v.z + v.w);
        ss = fmaf(v.x, v.x, ss); ss = fmaf(v.y, v.y, ss);
        ss = fmaf(v.z, v.z, ss); ss = fmaf(v.w, v.w, ss);
      }
      sm += __shfl_xor(sm, 1); sm += __shfl_xor(sm, 2);
      ss += __shfl_xor(ss, 1); ss += __shfl_xor(ss, 2);
      float mean = sm * (1.f / 128.f);
      float var  = ss * (1.f / 128.f) - mean * mean;
      float rstd = rsqrtf(var + 1e-5f);
      unsigned short* st = stage + wv * 2176 + r * 136 + q * 32;
      const float4* lwp = (const float4*)(lnzw + q * 32);
      const float4* lbp = (const float4*)(lnzb + q * 32);
      #pragma unroll
      for (int i = 0; i < 4; ++i) {
        float4 lw0 = lwp[2 * i], lw1 = lwp[2 * i + 1];
        float4 lb0 = lbp[2 * i], lb1 = lbp[2 * i + 1];
        int c = i * 8;
        unsigned o0 = pack2(fmaf((x[c]     - mean) * rstd, lw0.x, lb0.x),
                            fmaf((x[c + 1] - mean) * rstd, lw0.y, lb0.y));
        unsigned o1 = pack2(fmaf((x[c + 2] - mean) * rstd, lw0.z, lb0.z),
                            fmaf((x[c + 3] - mean) * rstd, lw0.w, lb0.w));
        unsigned o2 = pack2(fmaf((x[c + 4] - mean) * rstd, lw1.x, lb1.x),
                            fmaf((x[c + 5] - mean) * rstd, lw1.y, lb1.y));
        unsigned o3 = pack2(fmaf((x[c + 6] - mean) * rstd, lw1.z, lb1.z),
                            fmaf((x[c + 7] - mean) * rstd, lw1.w, lb1.w));
        uint4 ov; ov.x = o0; ov.y = o1; ov.z = o2; ov.w = o3;
        ((uint4*)st)[i] = ov;
      }
      __syncthreads();
      // B fragment: B[k][n], n = lane&15, k = kk*32 + (lane>>4)*8 + j
      int h = lane >> 4, lm = lane & 15;
      short8 bfrag[4];
      #pragma unroll
      for (int kk = 0; kk < 4; ++kk)
        #pragma unroll
        for (int jj = 0; jj < 8; ++jj)
          bfrag[kk][jj] = (short)f2bf(Wz[(size_t)(kk * 32 + h * 8 + jj) * CP + lm]);
      const unsigned short* sb = stage + wv * 2176;
      f32x4 acc = {0.f, 0.f, 0.f, 0.f};
      #pragma unroll
      for (int kk = 0; kk < 4; ++kk) {
        short8 af = *(const short8*)(sb + lm * 136 + kk * 32 + h * 8); // A[m=lm][k]
        acc = __builtin_amdgcn_mfma_f32_16x16x32_bf16(af, bfrag[kk], acc, 0, 0, 0);
      }
      // C/D: col(n)=lane&15, row(m)=(lane>>4)*4+reg
      #pragma unroll
      for (int jj = 0; jj < 4; ++jj)
        wlds[(wv * 16 + h * 4 + jj) * 16 + lm] = acc[jj];
    }
    __syncthreads();

    // ---- broadcast-add: out_plm[a,b,:] = plm[a,b,:] + w[t, tok[b], :] ----
    const float4* plm4 = (const float4*)plm;
    float4* out4 = (float4*)(out + (size_t)NA * CA);
    int ntask = (E - S) * 4;               // one task = (b, 4-channel float4)
    for (int a = s; a < e; ++a) {
      size_t rowbase = ((size_t)a << 10);
      for (int task = tid; task < ntask; task += 256) {
        int b = S + (task >> 2), quar = task & 3;
        int m = ((int)tokL[b] - m0) & 63;  // clamp: bad tok -> wrong value, not fault
        const float* w = wlds + m * 16 + quar * 4;
        size_t p4 = (rowbase + b) * 4 + quar;
        float4 pv = plm4[p4];
        float4 ov;
        ov.x = pv.x + w[0]; ov.y = pv.y + w[1];
        ov.z = pv.z + w[2]; ov.w = pv.w + w[3];
        out4[p4] = ov;
      }
    }
  } else if (blk < 1536) {
    int idx = (blk - 1024) * 256 + tid;    // over n_atom * c_atom
    int a = idx >> 7, j = idx & 127;
    int ta = (int)tok16[a] & 255;          // clamp
    out[idx] = cl[idx] + bfu(ytok[(size_t)ta * CA + j]);
  } else {
    int idx = (blk - 1536) * 256 + tid;
    int a = idx >> 7, j = idx & 127;
    float r0 = rl[a * 3 + 0], r1 = rl[a * 3 + 1], r2 = rl[a * 3 + 2];
    float v = ql[idx];
    v = fmaf(r0, Wr[j], v);
    v = fmaf(r1, Wr[CA + j], v);
    v = fmaf(r2, Wr[2 * CA + j], v);
    out[(size_t)NA * CA + (size_t)NA * NA * CP + idx] = v;
  }
}

extern "C" void kernel_launch(void* const* d_in, const int* in_sizes, int n_in,
                              void* d_out, int out_size, void* d_ws, size_t ws_size,
                              hipStream_t stream) {
  const float* a2t     = (const float*)d_in[0];
  const float* cl      = (const float*)d_in[1];
  const float* plm     = (const float*)d_in[2];
  const float* ql      = (const float*)d_in[3];
  const float* s_trunk = (const float*)d_in[4];
  const float* zij     = (const float*)d_in[5];
  const float* rl      = (const float*)d_in[6];
  const float* lnsw    = (const float*)d_in[7];
  const float* lnsb    = (const float*)d_in[8];
  const float* Ws      = (const float*)d_in[9];
  const float* lnzw    = (const float*)d_in[10];
  const float* lnzb    = (const float*)d_in[11];
  const float* Wz      = (const float*)d_in[12];
  const float* Wr      = (const float*)d_in[13];
  float* out = (float*)d_out;

  // workspace layout (66 KB): tok16 [1024 u16] | ytok [256*128 bf16]
  unsigned short* tok16 = (unsigned short*)d_ws;
  unsigned short* ytok  = (unsigned short*)d_ws + NA;

  prep_kernel<<<512, 256, 0, stream>>>(a2t, s_trunk, lnsw, lnsb, Ws, tok16, ytok);
  main_kernel<<<2048, 256, 0, stream>>>(cl, plm, ql, rl, Wr, zij, lnzw, lnzb, Wz,
                                        tok16, ytok, out);
}

// Round 4
// 213.481 us; speedup vs baseline: 1.0338x; 1.0338x over previous
//
#include <hip/hip_runtime.h>
#include <hip/hip_bf16.h>

// Problem constants
#define NA 1024   // n_atom
#define NT 256    // n_token
#define CS 384    // c_s
#define CZ 128    // c_z
#define CA 128    // c_atom
#define CP 16     // c_atom_pair

typedef __attribute__((ext_vector_type(8))) short short8;
typedef __attribute__((ext_vector_type(4))) float f32x4;

__device__ __forceinline__ float bfu(unsigned short v){ return __uint_as_float(((unsigned)v) << 16); }
__device__ __forceinline__ unsigned short f2bf(float f){
  unsigned u = __float_as_uint(f);
  return (unsigned short)((u + 0x7fffu + ((u >> 16) & 1u)) >> 16); // RNE
}
__device__ __forceinline__ unsigned pack2(float lo, float hi){
  return (unsigned)f2bf(lo) | ((unsigned)f2bf(hi) << 16);
}

__device__ __forceinline__ int lbound(const unsigned short* tokL, int key){
  int lo = 0, hi = NA;
  while (lo < hi) { int mid = (lo + hi) >> 1; if ((int)tokL[mid] < key) lo = mid + 1; else hi = mid; }
  return lo;
}

// ---------------------------------------------------------------------------
// prep: blocks [0,256)   role A: tok16[a] = argmax_t a2t[a,t]  (wave per atom)
//       blocks [256,512) role B: ytok[t,:] = LN_s(s_trunk[t])@W_s  (bf16 in ws)
// ws use: tok16 2 KB + ytok 64 KB = 66 KB
// ---------------------------------------------------------------------------
__global__ __launch_bounds__(256) void prep_kernel(
    const float* __restrict__ a2t,
    const float* __restrict__ s_trunk,
    const float* __restrict__ lnsw,
    const float* __restrict__ lnsb,
    const float* __restrict__ Ws,
    unsigned short* __restrict__ tok16,
    unsigned short* __restrict__ ytok)
{
  __shared__ float redS[4], redQ[4];
  __shared__ float lnbuf[CS];
  __shared__ float part[CA];

  const int blk  = blockIdx.x;
  const int tid  = threadIdx.x;
  const int lane = tid & 63;
  const int wv   = tid >> 6;

  if (blk < 256) {
    // ---- role A: one wave per atom; lane covers 4 one-hot f32 entries ----
    int a = blk * 4 + wv;
    float4 u = ((const float4*)(a2t + (size_t)a * NT))[lane];
    bool hit = (u.x != 0.f) | (u.y != 0.f) | (u.z != 0.f) | (u.w != 0.f);
    unsigned long long m = __ballot(hit);
    int fl = __ffsll(m) - 1;
    if (lane == fl) {
      int t = lane * 4;
      if (u.x != 0.f)      { /* +0 */ }
      else if (u.y != 0.f) t += 1;
      else if (u.z != 0.f) t += 2;
      else                 t += 3;
      tok16[a] = (unsigned short)t;
    }
  } else {
    // ---- role B: one block per token ----
    int tk = blk - 256;
    float f0 = 0.f, f1 = 0.f;
    if (tid < 192) {
      float2 v = ((const float2*)(s_trunk + (size_t)tk * CS))[tid];
      f0 = v.x; f1 = v.y;
    }
    float s = f0 + f1;
    float q = f0 * f0 + f1 * f1;
    #pragma unroll
    for (int m = 1; m < 64; m <<= 1) { s += __shfl_xor(s, m); q += __shfl_xor(q, m); }
    if (lane == 0) { redS[wv] = s; redQ[wv] = q; }
    __syncthreads();
    if (tid == 0) {
      float S = redS[0] + redS[1] + redS[2] + redS[3];
      float Q = redQ[0] + redQ[1] + redQ[2] + redQ[3];
      float mean = S * (1.f / 384.f);
      float var  = Q * (1.f / 384.f) - mean * mean;
      redS[0] = mean;
      redQ[0] = rsqrtf(var + 1e-5f);
    }
    __syncthreads();
    float mean = redS[0], rstd = redQ[0];
    if (tid < 192) {
      float2 w2 = ((const float2*)lnsw)[tid];
      float2 b2 = ((const float2*)lnsb)[tid];
      lnbuf[2 * tid]     = fmaf((f0 - mean) * rstd, w2.x, b2.x);
      lnbuf[2 * tid + 1] = fmaf((f1 - mean) * rstd, w2.y, b2.y);
    }
    __syncthreads();
    int j = tid & 127, half = tid >> 7;
    float acc = 0.f;
    int c0 = half * 192;
    #pragma unroll 8
    for (int c = c0; c < c0 + 192; ++c)
      acc = fmaf(lnbuf[c], Ws[(size_t)c * CA + j], acc);
    if (half) part[j] = acc;
    __syncthreads();
    if (!half) ytok[(size_t)tk * CA + j] = f2bf(acc + part[j]);
  }
}

// ---------------------------------------------------------------------------
// main: blocks [0,2048)     block = (token t, 64-token m-tile, a-slot of 2):
//                           w[t,m,:] via bf16 MFMA into LDS (aliased buffer),
//                           then batched broadcast-add into plm rows
//                           a = s+slot, s+slot+2, ... cols b in run(m-tile).
//       blocks [2048,2560)  cl_out = cl + ytok[tok[a]]
//       blocks [2560,3072)  ql_out = ql + rl @ W_r
// ---------------------------------------------------------------------------
__global__ __launch_bounds__(256) void main_kernel(
    const float* __restrict__ cl,
    const float* __restrict__ plm,
    const float* __restrict__ ql,
    const float* __restrict__ rl,
    const float* __restrict__ Wr,
    const float* __restrict__ zij,
    const float* __restrict__ lnzw,
    const float* __restrict__ lnzb,
    const float* __restrict__ Wz,
    const unsigned short* __restrict__ tok16,
    const unsigned short* __restrict__ ytok,
    float* __restrict__ out)
{
  const int blk = blockIdx.x;
  const int tid = threadIdx.x;

  if (blk < 2048) {
    __shared__ unsigned short tokL[NA];                 // 2 KB
    __shared__ __align__(16) unsigned short ubuf[4 * 16 * 136]; // 17.4 KB: stage, then wlds alias
    unsigned short* stage = ubuf;
    float* wlds = (float*)ubuf;                         // 64*16 f32 = 4 KB alias

    const int lane = tid & 63;
    const int wv   = tid >> 6;
    const int t    = blk >> 3;
    const int m0   = ((blk >> 1) & 3) << 6;
    const int slot = blk & 1;

    // stage tok[] into LDS (256 threads x 4 u16)
    ((uint2*)tokL)[tid] = ((const uint2*)tok16)[tid];
    __syncthreads();

    int s = lbound(tokL, t);
    int e = lbound(tokL, t + 1);
    if (s + slot >= e) return;             // no rows for this slot (uniform exit)
    int S = lbound(tokL, m0);
    int E = lbound(tokL, m0 + 64);
    if (S == E) return;                    // no atoms in this m-tile (uniform exit)

    // ---- w[t, m0+wv*16+r, :] = LN_z(zij[t,m])@W_z via MFMA -> wlds ----
    {
      int r = lane >> 2, q = lane & 3;     // 4 lanes per row, 32 channels each
      int mrow = m0 + wv * 16 + r;
      const float4* zp = (const float4*)(zij + ((size_t)t * NT + mrow) * CZ + q * 32);
      float x[32];
      float sm = 0.f, ss = 0.f;
      #pragma unroll
      for (int i = 0; i < 8; ++i) {
        float4 v = zp[i];
        x[4 * i]     = v.x; x[4 * i + 1] = v.y;
        x[4 * i + 2] = v.z; x[4 * i + 3] = v.w;
        sm += (v.x + v.y) + (v.z + v.w);
        ss = fmaf(v.x, v.x, ss); ss = fmaf(v.y, v.y, ss);
        ss = fmaf(v.z, v.z, ss); ss = fmaf(v.w, v.w, ss);
      }
      sm += __shfl_xor(sm, 1); sm += __shfl_xor(sm, 2);
      ss += __shfl_xor(ss, 1); ss += __shfl_xor(ss, 2);
      float mean = sm * (1.f / 128.f);
      float var  = ss * (1.f / 128.f) - mean * mean;
      float rstd = rsqrtf(var + 1e-5f);
      unsigned short* st = stage + wv * 2176 + r * 136 + q * 32;
      const float4* lwp = (const float4*)(lnzw + q * 32);
      const float4* lbp = (const float4*)(lnzb + q * 32);
      #pragma unroll
      for (int i = 0; i < 4; ++i) {
        float4 lw0 = lwp[2 * i], lw1 = lwp[2 * i + 1];
        float4 lb0 = lbp[2 * i], lb1 = lbp[2 * i + 1];
        int c = i * 8;
        unsigned o0 = pack2(fmaf((x[c]     - mean) * rstd, lw0.x, lb0.x),
                            fmaf((x[c + 1] - mean) * rstd, lw0.y, lb0.y));
        unsigned o1 = pack2(fmaf((x[c + 2] - mean) * rstd, lw0.z, lb0.z),
                            fmaf((x[c + 3] - mean) * rstd, lw0.w, lb0.w));
        unsigned o2 = pack2(fmaf((x[c + 4] - mean) * rstd, lw1.x, lb1.x),
                            fmaf((x[c + 5] - mean) * rstd, lw1.y, lb1.y));
        unsigned o3 = pack2(fmaf((x[c + 6] - mean) * rstd, lw1.z, lb1.z),
                            fmaf((x[c + 7] - mean) * rstd, lw1.w, lb1.w));
        uint4 ov; ov.x = o0; ov.y = o1; ov.z = o2; ov.w = o3;
        ((uint4*)st)[i] = ov;
      }
      __syncthreads();
      // B fragment: B[k][n], n = lane&15, k = kk*32 + (lane>>4)*8 + j
      int h = lane >> 4, lm = lane & 15;
      short8 bfrag[4];
      #pragma unroll
      for (int kk = 0; kk < 4; ++kk)
        #pragma unroll
        for (int jj = 0; jj < 8; ++jj)
          bfrag[kk][jj] = (short)f2bf(Wz[(size_t)(kk * 32 + h * 8 + jj) * CP + lm]);
      const unsigned short* sb = stage + wv * 2176;
      short8 af[4];
      #pragma unroll
      for (int kk = 0; kk < 4; ++kk)
        af[kk] = *(const short8*)(sb + lm * 136 + kk * 32 + h * 8); // A[m=lm][k]
      f32x4 acc = {0.f, 0.f, 0.f, 0.f};
      #pragma unroll
      for (int kk = 0; kk < 4; ++kk)
        acc = __builtin_amdgcn_mfma_f32_16x16x32_bf16(af[kk], bfrag[kk], acc, 0, 0, 0);
      __syncthreads();                     // all stage reads done -> safe to alias wlds
      // C/D: col(n)=lane&15, row(m)=(lane>>4)*4+reg
      #pragma unroll
      for (int jj = 0; jj < 4; ++jj)
        wlds[(wv * 16 + h * 4 + jj) * 16 + lm] = acc[jj];
    }
    __syncthreads();

    // ---- batched broadcast-add: out_plm[a,b,:] = plm[a,b,:] + w[t,tok[b],:] ----
    const float4* plm4 = (const float4*)plm;
    float4* out4 = (float4*)(out + (size_t)NA * CA);
    const int ntask = (E - S) * 4;         // one task = (b, 4-channel float4)
    for (int a = s + slot; a < e; a += 2) {
      size_t rowbase = ((size_t)a << 10);
      for (int base = 0; base < ntask; base += 1024) {
        float4 pv[4], wv4[4];
        size_t idx4[4];
        bool act[4];
        #pragma unroll
        for (int j = 0; j < 4; ++j) {
          int task = base + j * 256 + tid;
          act[j] = (task < ntask);
          int tt = act[j] ? task : 0;      // clamp -> unconditional in-bounds load
          int b = S + (tt >> 2), quar = tt & 3;
          int m = ((int)tokL[b] - m0) & 63;
          idx4[j] = (rowbase + b) * 4 + quar;
          wv4[j] = *(const float4*)(wlds + m * 16 + quar * 4);
          pv[j]  = plm4[idx4[j]];
        }
        #pragma unroll
        for (int j = 0; j < 4; ++j) {
          if (act[j]) {
            float4 ov;
            ov.x = pv[j].x + wv4[j].x; ov.y = pv[j].y + wv4[j].y;
            ov.z = pv[j].z + wv4[j].z; ov.w = pv[j].w + wv4[j].w;
            out4[idx4[j]] = ov;
          }
        }
      }
    }
  } else if (blk < 2560) {
    int idx = (blk - 2048) * 256 + tid;    // over n_atom * c_atom
    int a = idx >> 7, j = idx & 127;
    int ta = (int)tok16[a] & 255;          // clamp
    out[idx] = cl[idx] + bfu(ytok[(size_t)ta * CA + j]);
  } else {
    int idx = (blk - 2560) * 256 + tid;
    int a = idx >> 7, j = idx & 127;
    float r0 = rl[a * 3 + 0], r1 = rl[a * 3 + 1], r2 = rl[a * 3 + 2];
    float v = ql[idx];
    v = fmaf(r0, Wr[j], v);
    v = fmaf(r1, Wr[CA + j], v);
    v = fmaf(r2, Wr[2 * CA + j], v);
    out[(size_t)NA * CA + (size_t)NA * NA * CP + idx] = v;
  }
}

extern "C" void kernel_launch(void* const* d_in, const int* in_sizes, int n_in,
                              void* d_out, int out_size, void* d_ws, size_t ws_size,
                              hipStream_t stream) {
  const float* a2t     = (const float*)d_in[0];
  const float* cl      = (const float*)d_in[1];
  const float* plm     = (const float*)d_in[2];
  const float* ql      = (const float*)d_in[3];
  const float* s_trunk = (const float*)d_in[4];
  const float* zij     = (const float*)d_in[5];
  const float* rl      = (const float*)d_in[6];
  const float* lnsw    = (const float*)d_in[7];
  const float* lnsb    = (const float*)d_in[8];
  const float* Ws      = (const float*)d_in[9];
  const float* lnzw    = (const float*)d_in[10];
  const float* lnzb    = (const float*)d_in[11];
  const float* Wz      = (const float*)d_in[12];
  const float* Wr      = (const float*)d_in[13];
  float* out = (float*)d_out;

  // workspace layout (66 KB): tok16 [1024 u16] | ytok [256*128 bf16]
  unsigned short* tok16 = (unsigned short*)d_ws;
  unsigned short* ytok  = (unsigned short*)d_ws + NA;

  prep_kernel<<<512, 256, 0, stream>>>(a2t, s_trunk, lnsw, lnsb, Ws, tok16, ytok);
  main_kernel<<<3072, 256, 0, stream>>>(cl, plm, ql, rl, Wr, zij, lnzw, lnzb, Wz,
                                        tok16, ytok, out);
}

// Round 7
// 210.189 us; speedup vs baseline: 1.0500x; 1.0157x over previous
//
#include <hip/hip_runtime.h>
#include <hip/hip_bf16.h>

// Problem constants
#define NA 1024   // n_atom
#define NT 256    // n_token
#define CS 384    // c_s
#define CZ 128    // c_z
#define CA 128    // c_atom
#define CP 16     // c_atom_pair

typedef __attribute__((ext_vector_type(8))) short short8;
typedef __attribute__((ext_vector_type(4))) float f32x4;
typedef __attribute__((ext_vector_type(4))) unsigned int u32x4;

__device__ __forceinline__ float bflo(unsigned u){ return __uint_as_float(u << 16); }
__device__ __forceinline__ float bfhi(unsigned u){ return __uint_as_float(u & 0xffff0000u); }
__device__ __forceinline__ float bfu(unsigned short v){ return __uint_as_float(((unsigned)v) << 16); }
__device__ __forceinline__ unsigned short f2bf(float f){
  unsigned u = __float_as_uint(f);
  return (unsigned short)((u + 0x7fffu + ((u >> 16) & 1u)) >> 16); // RNE
}
__device__ __forceinline__ unsigned pack2(float lo, float hi){
  return (unsigned)f2bf(lo) | ((unsigned)f2bf(hi) << 16);
}

__device__ __forceinline__ int lbound(const unsigned short* tokL, int key){
  int lo = 0, hi = NA;
  while (lo < hi) { int mid = (lo + hi) >> 1; if ((int)tokL[mid] < key) lo = mid + 1; else hi = mid; }
  return lo;
}

// ===========================================================================
// PATH A (ws_size >= 2,164,736 B): materialize w_tm, then pure streaming pass.
// ws layout (FIXED): tok16 [1024 u16]  bytes [0, 2048)
//                    ytok  [32768 bf16] bytes [2048, 67584)
//                    w_tm  [1048576 bf16] bytes [67584, 2164736)
// R6 bug: wtm was at 66560, overlapping ytok's last 1024 B (tokens 252-255)
// -> cl absmax 3.68. Fixed offset 67584.
// ===========================================================================

// prep_full: blocks [0,256)    role A: tok16[a] (wave per atom)
//            blocks [256,512)  role B: ytok[t,:] = LN_s(s_trunk[t])@W_s (bf16)
//            blocks [512,1536) role C: w_tm[t,m,:] = LN_z(zij[t,m])@W_z (bf16, MFMA)
__global__ __launch_bounds__(256) void prep_full_kernel(
    const float* __restrict__ a2t,
    const float* __restrict__ s_trunk,
    const float* __restrict__ lnsw,
    const float* __restrict__ lnsb,
    const float* __restrict__ Ws,
    const float* __restrict__ zij,
    const float* __restrict__ lnzw,
    const float* __restrict__ lnzb,
    const float* __restrict__ Wz,
    unsigned short* __restrict__ tok16,
    unsigned short* __restrict__ ytok,
    unsigned short* __restrict__ wtm)
{
  __shared__ float redS[4], redQ[4];
  __shared__ float lnbuf[CS];
  __shared__ float part[CA];
  __shared__ __align__(16) unsigned short stage[4 * 16 * 136]; // 17.4 KB

  const int blk  = blockIdx.x;
  const int tid  = threadIdx.x;
  const int lane = tid & 63;
  const int wv   = tid >> 6;

  if (blk < 256) {
    // ---- role A ----
    int a = blk * 4 + wv;
    float4 u = ((const float4*)(a2t + (size_t)a * NT))[lane];
    bool hit = (u.x != 0.f) | (u.y != 0.f) | (u.z != 0.f) | (u.w != 0.f);
    unsigned long long m = __ballot(hit);
    int fl = __ffsll(m) - 1;
    if (lane == fl) {
      int t = lane * 4;
      if (u.x != 0.f)      { }
      else if (u.y != 0.f) t += 1;
      else if (u.z != 0.f) t += 2;
      else                 t += 3;
      tok16[a] = (unsigned short)t;
    }
  } else if (blk < 512) {
    // ---- role B ----
    int tk = blk - 256;
    float f0 = 0.f, f1 = 0.f;
    if (tid < 192) {
      float2 v = ((const float2*)(s_trunk + (size_t)tk * CS))[tid];
      f0 = v.x; f1 = v.y;
    }
    float s = f0 + f1;
    float q = f0 * f0 + f1 * f1;
    #pragma unroll
    for (int m = 1; m < 64; m <<= 1) { s += __shfl_xor(s, m); q += __shfl_xor(q, m); }
    if (lane == 0) { redS[wv] = s; redQ[wv] = q; }
    __syncthreads();
    if (tid == 0) {
      float S = redS[0] + redS[1] + redS[2] + redS[3];
      float Q = redQ[0] + redQ[1] + redQ[2] + redQ[3];
      float mean = S * (1.f / 384.f);
      float var  = Q * (1.f / 384.f) - mean * mean;
      redS[0] = mean;
      redQ[0] = rsqrtf(var + 1e-5f);
    }
    __syncthreads();
    float mean = redS[0], rstd = redQ[0];
    if (tid < 192) {
      float2 w2 = ((const float2*)lnsw)[tid];
      float2 b2 = ((const float2*)lnsb)[tid];
      lnbuf[2 * tid]     = fmaf((f0 - mean) * rstd, w2.x, b2.x);
      lnbuf[2 * tid + 1] = fmaf((f1 - mean) * rstd, w2.y, b2.y);
    }
    __syncthreads();
    int j = tid & 127, half = tid >> 7;
    float acc = 0.f;
    int c0 = half * 192;
    #pragma unroll 8
    for (int c = c0; c < c0 + 192; ++c)
      acc = fmaf(lnbuf[c], Ws[(size_t)c * CA + j], acc);
    if (half) part[j] = acc;
    __syncthreads();
    if (!half) ytok[(size_t)tk * CA + j] = f2bf(acc + part[j]);
  } else {
    // ---- role C: wave = 16 rows of the 65536 (t*256+m) rows ----
    int cb = blk - 512;
    int r = lane >> 2, q = lane & 3;       // 4 lanes per row, 32 channels each
    int rowbase = cb * 64 + wv * 16;
    const float4* zp = (const float4*)(zij + (size_t)(rowbase + r) * CZ + q * 32);
    float x[32];
    float sm = 0.f, ss = 0.f;
    #pragma unroll
    for (int i = 0; i < 8; ++i) {
      float4 v = zp[i];
      x[4 * i]     = v.x; x[4 * i + 1] = v.y;
      x[4 * i + 2] = v.z; x[4 * i + 3] = v.w;
      sm += (v.x + v.y) + (v.z + v.w);
      ss = fmaf(v.x, v.x, ss); ss = fmaf(v.y, v.y, ss);
      ss = fmaf(v.z, v.z, ss); ss = fmaf(v.w, v.w, ss);
    }
    sm += __shfl_xor(sm, 1); sm += __shfl_xor(sm, 2);
    ss += __shfl_xor(ss, 1); ss += __shfl_xor(ss, 2);
    float mean = sm * (1.f / 128.f);
    float var  = ss * (1.f / 128.f) - mean * mean;
    float rstd = rsqrtf(var + 1e-5f);
    unsigned short* st = stage + wv * 2176 + r * 136 + q * 32;
    const float4* lwp = (const float4*)(lnzw + q * 32);
    const float4* lbp = (const float4*)(lnzb + q * 32);
    #pragma unroll
    for (int i = 0; i < 4; ++i) {
      float4 lw0 = lwp[2 * i], lw1 = lwp[2 * i + 1];
      float4 lb0 = lbp[2 * i], lb1 = lbp[2 * i + 1];
      int c = i * 8;
      unsigned o0 = pack2(fmaf((x[c]     - mean) * rstd, lw0.x, lb0.x),
                          fmaf((x[c + 1] - mean) * rstd, lw0.y, lb0.y));
      unsigned o1 = pack2(fmaf((x[c + 2] - mean) * rstd, lw0.z, lb0.z),
                          fmaf((x[c + 3] - mean) * rstd, lw0.w, lb0.w));
      unsigned o2 = pack2(fmaf((x[c + 4] - mean) * rstd, lw1.x, lb1.x),
                          fmaf((x[c + 5] - mean) * rstd, lw1.y, lb1.y));
      unsigned o3 = pack2(fmaf((x[c + 6] - mean) * rstd, lw1.z, lb1.z),
                          fmaf((x[c + 7] - mean) * rstd, lw1.w, lb1.w));
      uint4 ov; ov.x = o0; ov.y = o1; ov.z = o2; ov.w = o3;
      ((uint4*)st)[i] = ov;
    }
    __syncthreads();
    // B fragment: B[k][n], n = lane&15, k = kk*32 + (lane>>4)*8 + j
    int h = lane >> 4, lm = lane & 15;
    short8 bfrag[4];
    #pragma unroll
    for (int kk = 0; kk < 4; ++kk)
      #pragma unroll
      for (int jj = 0; jj < 8; ++jj)
        bfrag[kk][jj] = (short)f2bf(Wz[(size_t)(kk * 32 + h * 8 + jj) * CP + lm]);
    const unsigned short* sb = stage + wv * 2176;
    f32x4 acc = {0.f, 0.f, 0.f, 0.f};
    #pragma unroll
    for (int kk = 0; kk < 4; ++kk) {
      short8 af = *(const short8*)(sb + lm * 136 + kk * 32 + h * 8); // A[m=lm][k]
      acc = __builtin_amdgcn_mfma_f32_16x16x32_bf16(af, bfrag[kk], acc, 0, 0, 0);
    }
    // C/D: col(n)=lane&15, row(m)=(lane>>4)*4+reg
    #pragma unroll
    for (int jj = 0; jj < 4; ++jj)
      wtm[(size_t)(rowbase + h * 4 + jj) * CP + lm] = f2bf(acc[jj]);
  }
}

// stream: blocks [0,4096)     thread = one pair (a,b): 32 B plm + w_tm row add
//         blocks [4096,4608)  cl_out = cl + ytok[tok[a]]
//         blocks [4608,5120)  ql_out = ql + rl @ W_r
__global__ __launch_bounds__(256) void stream_kernel(
    const float* __restrict__ cl,
    const float* __restrict__ plm,
    const float* __restrict__ ql,
    const float* __restrict__ rl,
    const float* __restrict__ Wr,
    const unsigned short* __restrict__ tok16,
    const unsigned short* __restrict__ ytok,
    const unsigned short* __restrict__ wtm,
    float* __restrict__ out)
{
  const int blk = blockIdx.x;
  const int tid = threadIdx.x;
  if (blk < 4096) {
    int p = blk * 256 + tid;               // pair index
    int a = p >> 10, b = p & 1023;         // a is block-uniform
    int ta = (int)tok16[a] & 255;
    int tb = (int)tok16[b] & 255;
    const u32x4* wp = (const u32x4*)(wtm + (((size_t)ta << 8) + (size_t)tb) * CP);
    u32x4 w01 = wp[0], w23 = wp[1];        // 16 bf16 (L2-resident 2 MB table)
    const f32x4* pp = (const f32x4*)plm + (size_t)p * 4;
    f32x4 p0 = __builtin_nontemporal_load(pp);
    f32x4 p1 = __builtin_nontemporal_load(pp + 1);
    f32x4 p2 = __builtin_nontemporal_load(pp + 2);
    f32x4 p3 = __builtin_nontemporal_load(pp + 3);
    f32x4 o0, o1, o2, o3;
    o0.x = p0.x + bflo(w01.x); o0.y = p0.y + bfhi(w01.x);
    o0.z = p0.z + bflo(w01.y); o0.w = p0.w + bfhi(w01.y);
    o1.x = p1.x + bflo(w01.z); o1.y = p1.y + bfhi(w01.z);
    o1.z = p1.z + bflo(w01.w); o1.w = p1.w + bfhi(w01.w);
    o2.x = p2.x + bflo(w23.x); o2.y = p2.y + bfhi(w23.x);
    o2.z = p2.z + bflo(w23.y); o2.w = p2.w + bfhi(w23.y);
    o3.x = p3.x + bflo(w23.z); o3.y = p3.y + bfhi(w23.z);
    o3.z = p3.z + bflo(w23.w); o3.w = p3.w + bfhi(w23.w);
    f32x4* op = (f32x4*)(out + (size_t)NA * CA) + (size_t)p * 4;
    __builtin_nontemporal_store(o0, op);
    __builtin_nontemporal_store(o1, op + 1);
    __builtin_nontemporal_store(o2, op + 2);
    __builtin_nontemporal_store(o3, op + 3);
  } else if (blk < 4608) {
    int idx = (blk - 4096) * 256 + tid;    // over n_atom * c_atom
    int a = idx >> 7, j = idx & 127;
    int ta = (int)tok16[a] & 255;
    out[idx] = cl[idx] + bfu(ytok[(size_t)ta * CA + j]);
  } else {
    int idx = (blk - 4608) * 256 + tid;
    int a = idx >> 7, j = idx & 127;
    float r0 = rl[a * 3 + 0], r1 = rl[a * 3 + 1], r2 = rl[a * 3 + 2];
    float v = ql[idx];
    v = fmaf(r0, Wr[j], v);
    v = fmaf(r1, Wr[CA + j], v);
    v = fmaf(r2, Wr[2 * CA + j], v);
    out[(size_t)NA * CA + (size_t)NA * NA * CP + idx] = v;
  }
}

// ===========================================================================
// PATH B (fallback, small ws): Round-4 kernels, proven correct at 66 KB ws.
// ===========================================================================
__global__ __launch_bounds__(256) void prep_kernel(
    const float* __restrict__ a2t,
    const float* __restrict__ s_trunk,
    const float* __restrict__ lnsw,
    const float* __restrict__ lnsb,
    const float* __restrict__ Ws,
    unsigned short* __restrict__ tok16,
    unsigned short* __restrict__ ytok)
{
  __shared__ float redS[4], redQ[4];
  __shared__ float lnbuf[CS];
  __shared__ float part[CA];

  const int blk  = blockIdx.x;
  const int tid  = threadIdx.x;
  const int lane = tid & 63;
  const int wv   = tid >> 6;

  if (blk < 256) {
    int a = blk * 4 + wv;
    float4 u = ((const float4*)(a2t + (size_t)a * NT))[lane];
    bool hit = (u.x != 0.f) | (u.y != 0.f) | (u.z != 0.f) | (u.w != 0.f);
    unsigned long long m = __ballot(hit);
    int fl = __ffsll(m) - 1;
    if (lane == fl) {
      int t = lane * 4;
      if (u.x != 0.f)      { }
      else if (u.y != 0.f) t += 1;
      else if (u.z != 0.f) t += 2;
      else                 t += 3;
      tok16[a] = (unsigned short)t;
    }
  } else {
    int tk = blk - 256;
    float f0 = 0.f, f1 = 0.f;
    if (tid < 192) {
      float2 v = ((const float2*)(s_trunk + (size_t)tk * CS))[tid];
      f0 = v.x; f1 = v.y;
    }
    float s = f0 + f1;
    float q = f0 * f0 + f1 * f1;
    #pragma unroll
    for (int m = 1; m < 64; m <<= 1) { s += __shfl_xor(s, m); q += __shfl_xor(q, m); }
    if (lane == 0) { redS[wv] = s; redQ[wv] = q; }
    __syncthreads();
    if (tid == 0) {
      float S = redS[0] + redS[1] + redS[2] + redS[3];
      float Q = redQ[0] + redQ[1] + redQ[2] + redQ[3];
      float mean = S * (1.f / 384.f);
      float var  = Q * (1.f / 384.f) - mean * mean;
      redS[0] = mean;
      redQ[0] = rsqrtf(var + 1e-5f);
    }
    __syncthreads();
    float mean = redS[0], rstd = redQ[0];
    if (tid < 192) {
      float2 w2 = ((const float2*)lnsw)[tid];
      float2 b2 = ((const float2*)lnsb)[tid];
      lnbuf[2 * tid]     = fmaf((f0 - mean) * rstd, w2.x, b2.x);
      lnbuf[2 * tid + 1] = fmaf((f1 - mean) * rstd, w2.y, b2.y);
    }
    __syncthreads();
    int j = tid & 127, half = tid >> 7;
    float acc = 0.f;
    int c0 = half * 192;
    #pragma unroll 8
    for (int c = c0; c < c0 + 192; ++c)
      acc = fmaf(lnbuf[c], Ws[(size_t)c * CA + j], acc);
    if (half) part[j] = acc;
    __syncthreads();
    if (!half) ytok[(size_t)tk * CA + j] = f2bf(acc + part[j]);
  }
}

__global__ __launch_bounds__(256) void main_kernel(
    const float* __restrict__ cl,
    const float* __restrict__ plm,
    const float* __restrict__ ql,
    const float* __restrict__ rl,
    const float* __restrict__ Wr,
    const float* __restrict__ zij,
    const float* __restrict__ lnzw,
    const float* __restrict__ lnzb,
    const float* __restrict__ Wz,
    const unsigned short* __restrict__ tok16,
    const unsigned short* __restrict__ ytok,
    float* __restrict__ out)
{
  const int blk = blockIdx.x;
  const int tid = threadIdx.x;

  if (blk < 2048) {
    __shared__ unsigned short tokL[NA];
    __shared__ __align__(16) unsigned short ubuf[4 * 16 * 136];
    unsigned short* stage = ubuf;
    float* wlds = (float*)ubuf;

    const int lane = tid & 63;
    const int wv   = tid >> 6;
    const int t    = blk >> 3;
    const int m0   = ((blk >> 1) & 3) << 6;
    const int slot = blk & 1;

    ((uint2*)tokL)[tid] = ((const uint2*)tok16)[tid];
    __syncthreads();

    int s = lbound(tokL, t);
    int e = lbound(tokL, t + 1);
    if (s + slot >= e) return;
    int S = lbound(tokL, m0);
    int E = lbound(tokL, m0 + 64);
    if (S == E) return;

    {
      int r = lane >> 2, q = lane & 3;
      int mrow = m0 + wv * 16 + r;
      const float4* zp = (const float4*)(zij + ((size_t)t * NT + mrow) * CZ + q * 32);
      float x[32];
      float sm = 0.f, ss = 0.f;
      #pragma unroll
      for (int i = 0; i < 8; ++i) {
        float4 v = zp[i];
        x[4 * i]     = v.x; x[4 * i + 1] = v.y;
        x[4 * i + 2] = v.z; x[4 * i + 3] = v.w;
        sm += (v.x + v.y) + (v.z + v.w);
        ss = fmaf(v.x, v.x, ss); ss = fmaf(v.y, v.y, ss);
        ss = fmaf(v.z, v.z, ss); ss = fmaf(v.w, v.w, ss);
      }
      sm += __shfl_xor(sm, 1); sm += __shfl_xor(sm, 2);
      ss += __shfl_xor(ss, 1); ss += __shfl_xor(ss, 2);
      float mean = sm * (1.f / 128.f);
      float var  = ss * (1.f / 128.f) - mean * mean;
      float rstd = rsqrtf(var + 1e-5f);
      unsigned short* st = stage + wv * 2176 + r * 136 + q * 32;
      const float4* lwp = (const float4*)(lnzw + q * 32);
      const float4* lbp = (const float4*)(lnzb + q * 32);
      #pragma unroll
      for (int i = 0; i < 4; ++i) {
        float4 lw0 = lwp[2 * i], lw1 = lwp[2 * i + 1];
        float4 lb0 = lbp[2 * i], lb1 = lbp[2 * i + 1];
        int c = i * 8;
        unsigned o0 = pack2(fmaf((x[c]     - mean) * rstd, lw0.x, lb0.x),
                            fmaf((x[c + 1] - mean) * rstd, lw0.y, lb0.y));
        unsigned o1 = pack2(fmaf((x[c + 2] - mean) * rstd, lw0.z, lb0.z),
                            fmaf((x[c + 3] - mean) * rstd, lw0.w, lb0.w));
        unsigned o2 = pack2(fmaf((x[c + 4] - mean) * rstd, lw1.x, lb1.x),
                            fmaf((x[c + 5] - mean) * rstd, lw1.y, lb1.y));
        unsigned o3 = pack2(fmaf((x[c + 6] - mean) * rstd, lw1.z, lb1.z),
                            fmaf((x[c + 7] - mean) * rstd, lw1.w, lb1.w));
        uint4 ov; ov.x = o0; ov.y = o1; ov.z = o2; ov.w = o3;
        ((uint4*)st)[i] = ov;
      }
      __syncthreads();
      int h = lane >> 4, lm = lane & 15;
      short8 bfrag[4];
      #pragma unroll
      for (int kk = 0; kk < 4; ++kk)
        #pragma unroll
        for (int jj = 0; jj < 8; ++jj)
          bfrag[kk][jj] = (short)f2bf(Wz[(size_t)(kk * 32 + h * 8 + jj) * CP + lm]);
      const unsigned short* sb = stage + wv * 2176;
      short8 af[4];
      #pragma unroll
      for (int kk = 0; kk < 4; ++kk)
        af[kk] = *(const short8*)(sb + lm * 136 + kk * 32 + h * 8);
      f32x4 acc = {0.f, 0.f, 0.f, 0.f};
      #pragma unroll
      for (int kk = 0; kk < 4; ++kk)
        acc = __builtin_amdgcn_mfma_f32_16x16x32_bf16(af[kk], bfrag[kk], acc, 0, 0, 0);
      __syncthreads();
      #pragma unroll
      for (int jj = 0; jj < 4; ++jj)
        wlds[(wv * 16 + h * 4 + jj) * 16 + lm] = acc[jj];
    }
    __syncthreads();

    const float4* plm4 = (const float4*)plm;
    float4* out4 = (float4*)(out + (size_t)NA * CA);
    const int ntask = (E - S) * 4;
    for (int a = s + slot; a < e; a += 2) {
      size_t rowbase = ((size_t)a << 10);
      for (int base = 0; base < ntask; base += 1024) {
        float4 pv[4], wv4[4];
        size_t idx4[4];
        bool act[4];
        #pragma unroll
        for (int j = 0; j < 4; ++j) {
          int task = base + j * 256 + tid;
          act[j] = (task < ntask);
          int tt = act[j] ? task : 0;
          int b = S + (tt >> 2), quar = tt & 3;
          int m = ((int)tokL[b] - m0) & 63;
          idx4[j] = (rowbase + b) * 4 + quar;
          wv4[j] = *(const float4*)(wlds + m * 16 + quar * 4);
          pv[j]  = plm4[idx4[j]];
        }
        #pragma unroll
        for (int j = 0; j < 4; ++j) {
          if (act[j]) {
            float4 ov;
            ov.x = pv[j].x + wv4[j].x; ov.y = pv[j].y + wv4[j].y;
            ov.z = pv[j].z + wv4[j].z; ov.w = pv[j].w + wv4[j].w;
            out4[idx4[j]] = ov;
          }
        }
      }
    }
  } else if (blk < 2560) {
    int idx = (blk - 2048) * 256 + tid;
    int a = idx >> 7, j = idx & 127;
    int ta = (int)tok16[a] & 255;
    out[idx] = cl[idx] + bfu(ytok[(size_t)ta * CA + j]);
  } else {
    int idx = (blk - 2560) * 256 + tid;
    int a = idx >> 7, j = idx & 127;
    float r0 = rl[a * 3 + 0], r1 = rl[a * 3 + 1], r2 = rl[a * 3 + 2];
    float v = ql[idx];
    v = fmaf(r0, Wr[j], v);
    v = fmaf(r1, Wr[CA + j], v);
    v = fmaf(r2, Wr[2 * CA + j], v);
    out[(size_t)NA * CA + (size_t)NA * NA * CP + idx] = v;
  }
}

extern "C" void kernel_launch(void* const* d_in, const int* in_sizes, int n_in,
                              void* d_out, int out_size, void* d_ws, size_t ws_size,
                              hipStream_t stream) {
  const float* a2t     = (const float*)d_in[0];
  const float* cl      = (const float*)d_in[1];
  const float* plm     = (const float*)d_in[2];
  const float* ql      = (const float*)d_in[3];
  const float* s_trunk = (const float*)d_in[4];
  const float* zij     = (const float*)d_in[5];
  const float* rl      = (const float*)d_in[6];
  const float* lnsw    = (const float*)d_in[7];
  const float* lnsb    = (const float*)d_in[8];
  const float* Ws      = (const float*)d_in[9];
  const float* lnzw    = (const float*)d_in[10];
  const float* lnzb    = (const float*)d_in[11];
  const float* Wz      = (const float*)d_in[12];
  const float* Wr      = (const float*)d_in[13];
  float* out = (float*)d_out;

  // ws layout (FIXED): tok16 @0 (2048 B) | ytok @2048 (65536 B) | wtm @67584 (2 MB)
  unsigned short* tok16 = (unsigned short*)d_ws;
  unsigned short* ytok  = (unsigned short*)((char*)d_ws + 2048);
  unsigned short* wtm   = (unsigned short*)((char*)d_ws + 67584);
  const size_t WS_NEEDED_A = 67584 + (size_t)NT * NT * CP * 2;  // 2,164,736 B

  if (ws_size >= WS_NEEDED_A) {
    // PATH A: materialize w_tm, pure streaming plm pass
    prep_full_kernel<<<1536, 256, 0, stream>>>(a2t, s_trunk, lnsw, lnsb, Ws,
                                               zij, lnzw, lnzb, Wz,
                                               tok16, ytok, wtm);
    stream_kernel<<<5120, 256, 0, stream>>>(cl, plm, ql, rl, Wr,
                                            tok16, ytok, wtm, out);
  } else {
    // PATH B: proven small-ws fallback (Round 4)
    prep_kernel<<<512, 256, 0, stream>>>(a2t, s_trunk, lnsw, lnsb, Ws, tok16, ytok);
    main_kernel<<<3072, 256, 0, stream>>>(cl, plm, ql, rl, Wr, zij, lnzw, lnzb, Wz,
                                          tok16, ytok, out);
  }
}

// Round 8
// 190.299 us; speedup vs baseline: 1.1597x; 1.1045x over previous
//
#include <hip/hip_runtime.h>
#include <hip/hip_bf16.h>

// Problem constants
#define NA 1024   // n_atom
#define NT 256    // n_token
#define CS 384    // c_s
#define CZ 128    // c_z
#define CA 128    // c_atom
#define CP 16     // c_atom_pair

typedef __attribute__((ext_vector_type(8))) short short8;
typedef __attribute__((ext_vector_type(4))) float f32x4;
typedef __attribute__((ext_vector_type(4))) unsigned int u32x4;

__device__ __forceinline__ float bflo(unsigned u){ return __uint_as_float(u << 16); }
__device__ __forceinline__ float bfhi(unsigned u){ return __uint_as_float(u & 0xffff0000u); }
__device__ __forceinline__ float bfu(unsigned short v){ return __uint_as_float(((unsigned)v) << 16); }
__device__ __forceinline__ unsigned short f2bf(float f){
  unsigned u = __float_as_uint(f);
  return (unsigned short)((u + 0x7fffu + ((u >> 16) & 1u)) >> 16); // RNE
}
__device__ __forceinline__ unsigned pack2(float lo, float hi){
  return (unsigned)f2bf(lo) | ((unsigned)f2bf(hi) << 16);
}

__device__ __forceinline__ int lbound(const unsigned short* tokL, int key){
  int lo = 0, hi = NA;
  while (lo < hi) { int mid = (lo + hi) >> 1; if ((int)tokL[mid] < key) lo = mid + 1; else hi = mid; }
  return lo;
}

// ===========================================================================
// PATH A (ws_size >= 2,164,736 B): materialize w_tm, then pure streaming pass.
// ws layout: tok16 [1024 u16]   bytes [0, 2048)
//            ytok  [32768 bf16]  bytes [2048, 67584)
//            w_tm  [1048576 bf16] bytes [67584, 2164736)
// R8: dropped nontemporal hints in stream_kernel — harness restores d_in /
// re-poisons d_out right before each timed launch, so plm/out are L2/L3-hot;
// NT loads bypassed the hot copy and NT stores doubled write traffic
// (WRITE 102 MB vs 70 MB expected; FETCH 37 MB).
// ===========================================================================

// prep_full: blocks [0,256)    role A: tok16[a] (wave per atom)
//            blocks [256,512)  role B: ytok[t,:] = LN_s(s_trunk[t])@W_s (bf16)
//            blocks [512,1536) role C: w_tm[t,m,:] = LN_z(zij[t,m])@W_z (bf16, MFMA)
__global__ __launch_bounds__(256) void prep_full_kernel(
    const float* __restrict__ a2t,
    const float* __restrict__ s_trunk,
    const float* __restrict__ lnsw,
    const float* __restrict__ lnsb,
    const float* __restrict__ Ws,
    const float* __restrict__ zij,
    const float* __restrict__ lnzw,
    const float* __restrict__ lnzb,
    const float* __restrict__ Wz,
    unsigned short* __restrict__ tok16,
    unsigned short* __restrict__ ytok,
    unsigned short* __restrict__ wtm)
{
  __shared__ float redS[4], redQ[4];
  __shared__ float lnbuf[CS];
  __shared__ float part[CA];
  __shared__ __align__(16) unsigned short stage[4 * 16 * 136]; // 17.4 KB

  const int blk  = blockIdx.x;
  const int tid  = threadIdx.x;
  const int lane = tid & 63;
  const int wv   = tid >> 6;

  if (blk < 256) {
    // ---- role A ----
    int a = blk * 4 + wv;
    float4 u = ((const float4*)(a2t + (size_t)a * NT))[lane];
    bool hit = (u.x != 0.f) | (u.y != 0.f) | (u.z != 0.f) | (u.w != 0.f);
    unsigned long long m = __ballot(hit);
    int fl = __ffsll(m) - 1;
    if (lane == fl) {
      int t = lane * 4;
      if (u.x != 0.f)      { }
      else if (u.y != 0.f) t += 1;
      else if (u.z != 0.f) t += 2;
      else                 t += 3;
      tok16[a] = (unsigned short)t;
    }
  } else if (blk < 512) {
    // ---- role B ----
    int tk = blk - 256;
    float f0 = 0.f, f1 = 0.f;
    if (tid < 192) {
      float2 v = ((const float2*)(s_trunk + (size_t)tk * CS))[tid];
      f0 = v.x; f1 = v.y;
    }
    float s = f0 + f1;
    float q = f0 * f0 + f1 * f1;
    #pragma unroll
    for (int m = 1; m < 64; m <<= 1) { s += __shfl_xor(s, m); q += __shfl_xor(q, m); }
    if (lane == 0) { redS[wv] = s; redQ[wv] = q; }
    __syncthreads();
    if (tid == 0) {
      float S = redS[0] + redS[1] + redS[2] + redS[3];
      float Q = redQ[0] + redQ[1] + redQ[2] + redQ[3];
      float mean = S * (1.f / 384.f);
      float var  = Q * (1.f / 384.f) - mean * mean;
      redS[0] = mean;
      redQ[0] = rsqrtf(var + 1e-5f);
    }
    __syncthreads();
    float mean = redS[0], rstd = redQ[0];
    if (tid < 192) {
      float2 w2 = ((const float2*)lnsw)[tid];
      float2 b2 = ((const float2*)lnsb)[tid];
      lnbuf[2 * tid]     = fmaf((f0 - mean) * rstd, w2.x, b2.x);
      lnbuf[2 * tid + 1] = fmaf((f1 - mean) * rstd, w2.y, b2.y);
    }
    __syncthreads();
    int j = tid & 127, half = tid >> 7;
    float acc = 0.f;
    int c0 = half * 192;
    #pragma unroll 8
    for (int c = c0; c < c0 + 192; ++c)
      acc = fmaf(lnbuf[c], Ws[(size_t)c * CA + j], acc);
    if (half) part[j] = acc;
    __syncthreads();
    if (!half) ytok[(size_t)tk * CA + j] = f2bf(acc + part[j]);
  } else {
    // ---- role C: wave = 16 rows of the 65536 (t*256+m) rows ----
    int cb = blk - 512;
    int r = lane >> 2, q = lane & 3;       // 4 lanes per row, 32 channels each
    int rowbase = cb * 64 + wv * 16;
    const float4* zp = (const float4*)(zij + (size_t)(rowbase + r) * CZ + q * 32);
    float x[32];
    float sm = 0.f, ss = 0.f;
    #pragma unroll
    for (int i = 0; i < 8; ++i) {
      float4 v = zp[i];
      x[4 * i]     = v.x; x[4 * i + 1] = v.y;
      x[4 * i + 2] = v.z; x[4 * i + 3] = v.w;
      sm += (v.x + v.y) + (v.z + v.w);
      ss = fmaf(v.x, v.x, ss); ss = fmaf(v.y, v.y, ss);
      ss = fmaf(v.z, v.z, ss); ss = fmaf(v.w, v.w, ss);
    }
    sm += __shfl_xor(sm, 1); sm += __shfl_xor(sm, 2);
    ss += __shfl_xor(ss, 1); ss += __shfl_xor(ss, 2);
    float mean = sm * (1.f / 128.f);
    float var  = ss * (1.f / 128.f) - mean * mean;
    float rstd = rsqrtf(var + 1e-5f);
    unsigned short* st = stage + wv * 2176 + r * 136 + q * 32;
    const float4* lwp = (const float4*)(lnzw + q * 32);
    const float4* lbp = (const float4*)(lnzb + q * 32);
    #pragma unroll
    for (int i = 0; i < 4; ++i) {
      float4 lw0 = lwp[2 * i], lw1 = lwp[2 * i + 1];
      float4 lb0 = lbp[2 * i], lb1 = lbp[2 * i + 1];
      int c = i * 8;
      unsigned o0 = pack2(fmaf((x[c]     - mean) * rstd, lw0.x, lb0.x),
                          fmaf((x[c + 1] - mean) * rstd, lw0.y, lb0.y));
      unsigned o1 = pack2(fmaf((x[c + 2] - mean) * rstd, lw0.z, lb0.z),
                          fmaf((x[c + 3] - mean) * rstd, lw0.w, lb0.w));
      unsigned o2 = pack2(fmaf((x[c + 4] - mean) * rstd, lw1.x, lb1.x),
                          fmaf((x[c + 5] - mean) * rstd, lw1.y, lb1.y));
      unsigned o3 = pack2(fmaf((x[c + 6] - mean) * rstd, lw1.z, lb1.z),
                          fmaf((x[c + 7] - mean) * rstd, lw1.w, lb1.w));
      uint4 ov; ov.x = o0; ov.y = o1; ov.z = o2; ov.w = o3;
      ((uint4*)st)[i] = ov;
    }
    __syncthreads();
    // B fragment: B[k][n], n = lane&15, k = kk*32 + (lane>>4)*8 + j
    int h = lane >> 4, lm = lane & 15;
    short8 bfrag[4];
    #pragma unroll
    for (int kk = 0; kk < 4; ++kk)
      #pragma unroll
      for (int jj = 0; jj < 8; ++jj)
        bfrag[kk][jj] = (short)f2bf(Wz[(size_t)(kk * 32 + h * 8 + jj) * CP + lm]);
    const unsigned short* sb = stage + wv * 2176;
    f32x4 acc = {0.f, 0.f, 0.f, 0.f};
    #pragma unroll
    for (int kk = 0; kk < 4; ++kk) {
      short8 af = *(const short8*)(sb + lm * 136 + kk * 32 + h * 8); // A[m=lm][k]
      acc = __builtin_amdgcn_mfma_f32_16x16x32_bf16(af, bfrag[kk], acc, 0, 0, 0);
    }
    // C/D: col(n)=lane&15, row(m)=(lane>>4)*4+reg
    #pragma unroll
    for (int jj = 0; jj < 4; ++jj)
      wtm[(size_t)(rowbase + h * 4 + jj) * CP + lm] = f2bf(acc[jj]);
  }
}

// stream: blocks [0,4096)     thread = one pair (a,b): 64 B plm + w_tm row add
//         blocks [4096,4608)  cl_out = cl + ytok[tok[a]]
//         blocks [4608,5120)  ql_out = ql + rl @ W_r
__global__ __launch_bounds__(256) void stream_kernel(
    const float* __restrict__ cl,
    const float* __restrict__ plm,
    const float* __restrict__ ql,
    const float* __restrict__ rl,
    const float* __restrict__ Wr,
    const unsigned short* __restrict__ tok16,
    const unsigned short* __restrict__ ytok,
    const unsigned short* __restrict__ wtm,
    float* __restrict__ out)
{
  const int blk = blockIdx.x;
  const int tid = threadIdx.x;
  if (blk < 4096) {
    int p = blk * 256 + tid;               // pair index
    int a = p >> 10, b = p & 1023;         // a is block-uniform
    int ta = (int)tok16[a] & 255;
    int tb = (int)tok16[b] & 255;
    const u32x4* wp = (const u32x4*)(wtm + (((size_t)ta << 8) + (size_t)tb) * CP);
    u32x4 w01 = wp[0], w23 = wp[1];        // 16 bf16 (L2-resident 2 MB table)
    const f32x4* pp = (const f32x4*)plm + (size_t)p * 4;
    f32x4 p0 = pp[0];
    f32x4 p1 = pp[1];
    f32x4 p2 = pp[2];
    f32x4 p3 = pp[3];
    f32x4 o0, o1, o2, o3;
    o0.x = p0.x + bflo(w01.x); o0.y = p0.y + bfhi(w01.x);
    o0.z = p0.z + bflo(w01.y); o0.w = p0.w + bfhi(w01.y);
    o1.x = p1.x + bflo(w01.z); o1.y = p1.y + bfhi(w01.z);
    o1.z = p1.z + bflo(w01.w); o1.w = p1.w + bfhi(w01.w);
    o2.x = p2.x + bflo(w23.x); o2.y = p2.y + bfhi(w23.x);
    o2.z = p2.z + bflo(w23.y); o2.w = p2.w + bfhi(w23.y);
    o3.x = p3.x + bflo(w23.z); o3.y = p3.y + bfhi(w23.z);
    o3.z = p3.z + bflo(w23.w); o3.w = p3.w + bfhi(w23.w);
    f32x4* op = (f32x4*)(out + (size_t)NA * CA) + (size_t)p * 4;
    op[0] = o0;
    op[1] = o1;
    op[2] = o2;
    op[3] = o3;
  } else if (blk < 4608) {
    int idx = (blk - 4096) * 256 + tid;    // over n_atom * c_atom
    int a = idx >> 7, j = idx & 127;
    int ta = (int)tok16[a] & 255;
    out[idx] = cl[idx] + bfu(ytok[(size_t)ta * CA + j]);
  } else {
    int idx = (blk - 4608) * 256 + tid;
    int a = idx >> 7, j = idx & 127;
    float r0 = rl[a * 3 + 0], r1 = rl[a * 3 + 1], r2 = rl[a * 3 + 2];
    float v = ql[idx];
    v = fmaf(r0, Wr[j], v);
    v = fmaf(r1, Wr[CA + j], v);
    v = fmaf(r2, Wr[2 * CA + j], v);
    out[(size_t)NA * CA + (size_t)NA * NA * CP + idx] = v;
  }
}

// ===========================================================================
// PATH B (fallback, small ws): Round-4 kernels, proven correct at 66 KB ws.
// ===========================================================================
__global__ __launch_bounds__(256) void prep_kernel(
    const float* __restrict__ a2t,
    const float* __restrict__ s_trunk,
    const float* __restrict__ lnsw,
    const float* __restrict__ lnsb,
    const float* __restrict__ Ws,
    unsigned short* __restrict__ tok16,
    unsigned short* __restrict__ ytok)
{
  __shared__ float redS[4], redQ[4];
  __shared__ float lnbuf[CS];
  __shared__ float part[CA];

  const int blk  = blockIdx.x;
  const int tid  = threadIdx.x;
  const int lane = tid & 63;
  const int wv   = tid >> 6;

  if (blk < 256) {
    int a = blk * 4 + wv;
    float4 u = ((const float4*)(a2t + (size_t)a * NT))[lane];
    bool hit = (u.x != 0.f) | (u.y != 0.f) | (u.z != 0.f) | (u.w != 0.f);
    unsigned long long m = __ballot(hit);
    int fl = __ffsll(m) - 1;
    if (lane == fl) {
      int t = lane * 4;
      if (u.x != 0.f)      { }
      else if (u.y != 0.f) t += 1;
      else if (u.z != 0.f) t += 2;
      else                 t += 3;
      tok16[a] = (unsigned short)t;
    }
  } else {
    int tk = blk - 256;
    float f0 = 0.f, f1 = 0.f;
    if (tid < 192) {
      float2 v = ((const float2*)(s_trunk + (size_t)tk * CS))[tid];
      f0 = v.x; f1 = v.y;
    }
    float s = f0 + f1;
    float q = f0 * f0 + f1 * f1;
    #pragma unroll
    for (int m = 1; m < 64; m <<= 1) { s += __shfl_xor(s, m); q += __shfl_xor(q, m); }
    if (lane == 0) { redS[wv] = s; redQ[wv] = q; }
    __syncthreads();
    if (tid == 0) {
      float S = redS[0] + redS[1] + redS[2] + redS[3];
      float Q = redQ[0] + redQ[1] + redQ[2] + redQ[3];
      float mean = S * (1.f / 384.f);
      float var  = Q * (1.f / 384.f) - mean * mean;
      redS[0] = mean;
      redQ[0] = rsqrtf(var + 1e-5f);
    }
    __syncthreads();
    float mean = redS[0], rstd = redQ[0];
    if (tid < 192) {
      float2 w2 = ((const float2*)lnsw)[tid];
      float2 b2 = ((const float2*)lnsb)[tid];
      lnbuf[2 * tid]     = fmaf((f0 - mean) * rstd, w2.x, b2.x);
      lnbuf[2 * tid + 1] = fmaf((f1 - mean) * rstd, w2.y, b2.y);
    }
    __syncthreads();
    int j = tid & 127, half = tid >> 7;
    float acc = 0.f;
    int c0 = half * 192;
    #pragma unroll 8
    for (int c = c0; c < c0 + 192; ++c)
      acc = fmaf(lnbuf[c], Ws[(size_t)c * CA + j], acc);
    if (half) part[j] = acc;
    __syncthreads();
    if (!half) ytok[(size_t)tk * CA + j] = f2bf(acc + part[j]);
  }
}

__global__ __launch_bounds__(256) void main_kernel(
    const float* __restrict__ cl,
    const float* __restrict__ plm,
    const float* __restrict__ ql,
    const float* __restrict__ rl,
    const float* __restrict__ Wr,
    const float* __restrict__ zij,
    const float* __restrict__ lnzw,
    const float* __restrict__ lnzb,
    const float* __restrict__ Wz,
    const unsigned short* __restrict__ tok16,
    const unsigned short* __restrict__ ytok,
    float* __restrict__ out)
{
  const int blk = blockIdx.x;
  const int tid = threadIdx.x;

  if (blk < 2048) {
    __shared__ unsigned short tokL[NA];
    __shared__ __align__(16) unsigned short ubuf[4 * 16 * 136];
    unsigned short* stage = ubuf;
    float* wlds = (float*)ubuf;

    const int lane = tid & 63;
    const int wv   = tid >> 6;
    const int t    = blk >> 3;
    const int m0   = ((blk >> 1) & 3) << 6;
    const int slot = blk & 1;

    ((uint2*)tokL)[tid] = ((const uint2*)tok16)[tid];
    __syncthreads();

    int s = lbound(tokL, t);
    int e = lbound(tokL, t + 1);
    if (s + slot >= e) return;
    int S = lbound(tokL, m0);
    int E = lbound(tokL, m0 + 64);
    if (S == E) return;

    {
      int r = lane >> 2, q = lane & 3;
      int mrow = m0 + wv * 16 + r;
      const float4* zp = (const float4*)(zij + ((size_t)t * NT + mrow) * CZ + q * 32);
      float x[32];
      float sm = 0.f, ss = 0.f;
      #pragma unroll
      for (int i = 0; i < 8; ++i) {
        float4 v = zp[i];
        x[4 * i]     = v.x; x[4 * i + 1] = v.y;
        x[4 * i + 2] = v.z; x[4 * i + 3] = v.w;
        sm += (v.x + v.y) + (v.z + v.w);
        ss = fmaf(v.x, v.x, ss); ss = fmaf(v.y, v.y, ss);
        ss = fmaf(v.z, v.z, ss); ss = fmaf(v.w, v.w, ss);
      }
      sm += __shfl_xor(sm, 1); sm += __shfl_xor(sm, 2);
      ss += __shfl_xor(ss, 1); ss += __shfl_xor(ss, 2);
      float mean = sm * (1.f / 128.f);
      float var  = ss * (1.f / 128.f) - mean * mean;
      float rstd = rsqrtf(var + 1e-5f);
      unsigned short* st = stage + wv * 2176 + r * 136 + q * 32;
      const float4* lwp = (const float4*)(lnzw + q * 32);
      const float4* lbp = (const float4*)(lnzb + q * 32);
      #pragma unroll
      for (int i = 0; i < 4; ++i) {
        float4 lw0 = lwp[2 * i], lw1 = lwp[2 * i + 1];
        float4 lb0 = lbp[2 * i], lb1 = lbp[2 * i + 1];
        int c = i * 8;
        unsigned o0 = pack2(fmaf((x[c]     - mean) * rstd, lw0.x, lb0.x),
                            fmaf((x[c + 1] - mean) * rstd, lw0.y, lb0.y));
        unsigned o1 = pack2(fmaf((x[c + 2] - mean) * rstd, lw0.z, lb0.z),
                            fmaf((x[c + 3] - mean) * rstd, lw0.w, lb0.w));
        unsigned o2 = pack2(fmaf((x[c + 4] - mean) * rstd, lw1.x, lb1.x),
                            fmaf((x[c + 5] - mean) * rstd, lw1.y, lb1.y));
        unsigned o3 = pack2(fmaf((x[c + 6] - mean) * rstd, lw1.z, lb1.z),
                            fmaf((x[c + 7] - mean) * rstd, lw1.w, lb1.w));
        uint4 ov; ov.x = o0; ov.y = o1; ov.z = o2; ov.w = o3;
        ((uint4*)st)[i] = ov;
      }
      __syncthreads();
      int h = lane >> 4, lm = lane & 15;
      short8 bfrag[4];
      #pragma unroll
      for (int kk = 0; kk < 4; ++kk)
        #pragma unroll
        for (int jj = 0; jj < 8; ++jj)
          bfrag[kk][jj] = (short)f2bf(Wz[(size_t)(kk * 32 + h * 8 + jj) * CP + lm]);
      const unsigned short* sb = stage + wv * 2176;
      short8 af[4];
      #pragma unroll
      for (int kk = 0; kk < 4; ++kk)
        af[kk] = *(const short8*)(sb + lm * 136 + kk * 32 + h * 8);
      f32x4 acc = {0.f, 0.f, 0.f, 0.f};
      #pragma unroll
      for (int kk = 0; kk < 4; ++kk)
        acc = __builtin_amdgcn_mfma_f32_16x16x32_bf16(af[kk], bfrag[kk], acc, 0, 0, 0);
      __syncthreads();
      #pragma unroll
      for (int jj = 0; jj < 4; ++jj)
        wlds[(wv * 16 + h * 4 + jj) * 16 + lm] = acc[jj];
    }
    __syncthreads();

    const float4* plm4 = (const float4*)plm;
    float4* out4 = (float4*)(out + (size_t)NA * CA);
    const int ntask = (E - S) * 4;
    for (int a = s + slot; a < e; a += 2) {
      size_t rowbase = ((size_t)a << 10);
      for (int base = 0; base < ntask; base += 1024) {
        float4 pv[4], wv4[4];
        size_t idx4[4];
        bool act[4];
        #pragma unroll
        for (int j = 0; j < 4; ++j) {
          int task = base + j * 256 + tid;
          act[j] = (task < ntask);
          int tt = act[j] ? task : 0;
          int b = S + (tt >> 2), quar = tt & 3;
          int m = ((int)tokL[b] - m0) & 63;
          idx4[j] = (rowbase + b) * 4 + quar;
          wv4[j] = *(const float4*)(wlds + m * 16 + quar * 4);
          pv[j]  = plm4[idx4[j]];
        }
        #pragma unroll
        for (int j = 0; j < 4; ++j) {
          if (act[j]) {
            float4 ov;
            ov.x = pv[j].x + wv4[j].x; ov.y = pv[j].y + wv4[j].y;
            ov.z = pv[j].z + wv4[j].z; ov.w = pv[j].w + wv4[j].w;
            out4[idx4[j]] = ov;
          }
        }
      }
    }
  } else if (blk < 2560) {
    int idx = (blk - 2048) * 256 + tid;
    int a = idx >> 7, j = idx & 127;
    int ta = (int)tok16[a] & 255;
    out[idx] = cl[idx] + bfu(ytok[(size_t)ta * CA + j]);
  } else {
    int idx = (blk - 2560) * 256 + tid;
    int a = idx >> 7, j = idx & 127;
    float r0 = rl[a * 3 + 0], r1 = rl[a * 3 + 1], r2 = rl[a * 3 + 2];
    float v = ql[idx];
    v = fmaf(r0, Wr[j], v);
    v = fmaf(r1, Wr[CA + j], v);
    v = fmaf(r2, Wr[2 * CA + j], v);
    out[(size_t)NA * CA + (size_t)NA * NA * CP + idx] = v;
  }
}

extern "C" void kernel_launch(void* const* d_in, const int* in_sizes, int n_in,
                              void* d_out, int out_size, void* d_ws, size_t ws_size,
                              hipStream_t stream) {
  const float* a2t     = (const float*)d_in[0];
  const float* cl      = (const float*)d_in[1];
  const float* plm     = (const float*)d_in[2];
  const float* ql      = (const float*)d_in[3];
  const float* s_trunk = (const float*)d_in[4];
  const float* zij     = (const float*)d_in[5];
  const float* rl      = (const float*)d_in[6];
  const float* lnsw    = (const float*)d_in[7];
  const float* lnsb    = (const float*)d_in[8];
  const float* Ws      = (const float*)d_in[9];
  const float* lnzw    = (const float*)d_in[10];
  const float* lnzb    = (const float*)d_in[11];
  const float* Wz      = (const float*)d_in[12];
  const float* Wr      = (const float*)d_in[13];
  float* out = (float*)d_out;

  // ws layout: tok16 @0 (2048 B) | ytok @2048 (65536 B) | wtm @67584 (2 MB)
  unsigned short* tok16 = (unsigned short*)d_ws;
  unsigned short* ytok  = (unsigned short*)((char*)d_ws + 2048);
  unsigned short* wtm   = (unsigned short*)((char*)d_ws + 67584);
  const size_t WS_NEEDED_A = 67584 + (size_t)NT * NT * CP * 2;  // 2,164,736 B

  if (ws_size >= WS_NEEDED_A) {
    // PATH A: materialize w_tm, pure streaming plm pass
    prep_full_kernel<<<1536, 256, 0, stream>>>(a2t, s_trunk, lnsw, lnsb, Ws,
                                               zij, lnzw, lnzb, Wz,
                                               tok16, ytok, wtm);
    stream_kernel<<<5120, 256, 0, stream>>>(cl, plm, ql, rl, Wr,
                                            tok16, ytok, wtm, out);
  } else {
    // PATH B: proven small-ws fallback (Round 4)
    prep_kernel<<<512, 256, 0, stream>>>(a2t, s_trunk, lnsw, lnsb, Ws, tok16, ytok);
    main_kernel<<<3072, 256, 0, stream>>>(cl, plm, ql, rl, Wr, zij, lnzw, lnzb, Wz,
                                          tok16, ytok, out);
  }
}